// Round 8
// baseline (268.180 us; speedup 1.0000x reference)
//
#include <hip/hip_runtime.h>
#include <stdint.h>

// LSTM fused: B=8192, T=128, I=32, H=64, OUT=8. fp32 internal state, bf16 MFMA.
// R16 = R15 (best, 127.5us) with ONE orthogonal change: SWAPPED MFMA
// orientation (gates^T = W·h^T). mfma(wf, h_frag, acc) instead of
// mfma(h_frag, wf, acc). A-frag and B-frag lane layouts are the same pattern,
// so ALL loads (wf, hbuf b128 reads, xbuf reads) are byte-identical to R15;
// only the C/D meaning flips: lane (q,tn) holds gates for batch tn (col) x
// units wid*16+q*4+r (row). Wins:
//   - h-write: 4 scattered ds_write_b16 (288B-apart rows) -> ONE packed
//     ds_write_b64 in a single row (1 DS op, 1 address, shorter pre-barrier
//     lgkm drain — the write->drain->barrier tail was the last named
//     critical-path segment).
//   - epilogue hfin write contiguous.
//   - bias indexed by q*4+r instead of tn (startup-only change).
// Accumulation order per output unchanged (x first, then h k0..31, k32..63)
// -> same numerics, absmax expected 0.001953125.
// Ledger: R15 {reg-carried x-frag, accx at step top, cst in 2log2e domain}
// +3.5us; R14 {weight-prescale of exp2 scale, setprio on MFMA cluster} +5us;
// R11 {loads hoisted to step top, dependent MFMAs off the lgkm wait}.
// Structure frozen: 2 waves/SIMD optimum (R9 8-wave barrier 184us, R12
// 4 chains garbage rows 154us, R13 1 wave/SIMD 185us). R10: bank conflicts
// off-path, HPAD=144 known-good.
// NaN ledger: R1/R5/R7 (vector weight loads, plain body) and R6 (K=16 f16)
// all NaN'd; R2/R3/R8/R11/R14/R15 (scalar loads + sniff dispatcher) passed.
// Do not reintroduce those factors without an isolated A/B.

#define T_STEPS 128
#define ISZ 32
#define HSZ 64
#define B_TOT 8192
#define B_TILE 16
#define T_CHUNK 32
#define HPAD 144

typedef short bf16x8 __attribute__((ext_vector_type(8)));
typedef float f32x4 __attribute__((ext_vector_type(4)));

#define LOG2E 1.44269504088896340736f

__device__ __forceinline__ float bf2f(unsigned short s) {
    union { unsigned int u; float f; } v; v.u = ((unsigned int)s) << 16; return v.f;
}
__device__ __forceinline__ unsigned short f2bf(float f) {
    union { float f; unsigned int u; } v; v.f = f;
    unsigned int u = v.u;
    return (unsigned short)((u + 0x7fffu + ((u >> 16) & 1u)) >> 16);  // RNE
}
// prescaled-gate helpers: z already carries the exp2 scale (folded into W).
// sig_pre: z = -LOG2E*x -> sigmoid(x). z->+inf: exp2->inf, rcp->0. Safe.
__device__ __forceinline__ float sig_pre(float z) {
    return __builtin_amdgcn_rcpf(1.0f + __builtin_amdgcn_exp2f(z));
}

template <bool F32>
__device__ __forceinline__ float ldin(const void* p, size_t i) {
    if (F32) return ((const float*)p)[i];
    return bf2f(((const unsigned short*)p)[i]);
}

template <bool F32>
__device__ __forceinline__ void run_body(
    const void* xv, const void* Wihv, const void* Whhv, const void* bihv,
    const void* bhhv, const void* Wfcv, const void* bfcv, void* outv,
    unsigned short (&hbuf)[2][B_TILE][HPAD],
    unsigned short (&xbuf)[T_CHUNK][B_TILE][40],
    float (&hfin)[B_TILE][HSZ + 4])
{
    const int tid  = threadIdx.x;
    const int wid  = tid >> 6;
    const int lane = tid & 63;
    const int q    = lane >> 4;   // A/B frag k-quad; C/D row-quad
    const int tn   = lane & 15;   // frag row/col index; C/D col = batch tn
    const int u    = wid * 16 + tn;       // weight row this lane LOADS (frag layout)
    const int urow = wid * 16 + q * 4;    // unit base this lane OWNS in C/D
    const int b0   = blockIdx.x * B_TILE;

    // Weight frags, loaded once (scalar loads — see NaN ledger). Byte-identical
    // to R15: frag(m=tn, k=q*8+j) = W[g*64+wid*16+tn][k] — serves as the MFMA
    // A-operand in the swapped orientation. Exp2 scale folded in: i/f/o rows
    // x (-LOG2E), g rows x (+2*LOG2E), fp32 mul BEFORE the single bf16 round.
    bf16x8 wf[4][3];
    f32x4 biasC[4];   // bias as C-operand; element r = unit urow+r (swapped C/D)
    #pragma unroll
    for (int g = 0; g < 4; ++g) {
        const float sc = (g == 2) ? (2.0f * LOG2E) : (-LOG2E);
        const int row = g * HSZ + u;
        #pragma unroll
        for (int j = 0; j < 8; ++j) {
            wf[g][0][j] = (short)f2bf(sc * ldin<F32>(Whhv, row * HSZ + q * 8 + j));
            wf[g][1][j] = (short)f2bf(sc * ldin<F32>(Whhv, row * HSZ + 32 + q * 8 + j));
            wf[g][2][j] = (short)f2bf(sc * ldin<F32>(Wihv, row * ISZ + q * 8 + j));
        }
        #pragma unroll
        for (int e = 0; e < 4; ++e) {
            const int br = g * HSZ + urow + e;   // bias row = OWNED unit
            biasC[g][e] = sc * (ldin<F32>(bihv, br) + ldin<F32>(bhhv, br));
        }
    }

    // h(0) = 0
    for (int i = tid; i < 2 * B_TILE * HPAD; i += 256) ((unsigned short*)hbuf)[i] = 0;

    // c-state in the 2*log2e domain; lane state = (batch tn, units urow+r).
    float cstS[4] = {0.f, 0.f, 0.f, 0.f};
    float hl[4]   = {0.f, 0.f, 0.f, 0.f};

    for (int tc = 0; tc < T_STEPS / T_CHUNK; ++tc) {
        // stage x[b0..+16)[tc*32..+32)[0..32) -> xbuf[t][m][k]; prev chunk's
        // reads finished at the last step's barrier, so no barrier needed here.
        if (F32) {
            const float* xf = (const float*)xv;
            for (int idx = tid; idx < B_TILE * T_CHUNK * 4; idx += 256) {
                const int m  = idx >> 7;
                const int rm = idx & 127;
                const int tl = rm >> 2;
                const int ch = rm & 3;
                const size_t base = ((size_t)(b0 + m) * T_STEPS + (tc * T_CHUNK + tl)) * ISZ + ch * 8;
                const f32x4 v0 = *(const f32x4*)(xf + base);
                const f32x4 v1 = *(const f32x4*)(xf + base + 4);
                bf16x8 w;
                #pragma unroll
                for (int j = 0; j < 4; ++j) {
                    w[j]     = (short)f2bf(v0[j]);
                    w[4 + j] = (short)f2bf(v1[j]);
                }
                *(bf16x8*)&xbuf[tl][m][ch * 8] = w;
            }
        } else {
            const unsigned short* xu = (const unsigned short*)xv;
            for (int idx = tid; idx < B_TILE * T_CHUNK * 4; idx += 256) {
                const int m  = idx >> 7;
                const int rm = idx & 127;
                const int tl = rm >> 2;
                const int ch = rm & 3;
                const uint4 v = *(const uint4*)(xu + ((size_t)(b0 + m) * T_STEPS + (tc * T_CHUNK + tl)) * ISZ + ch * 8);
                *(uint4*)&xbuf[tl][m][ch * 8] = v;
            }
        }
        __syncthreads();

        // chunk prologue: register-carry the x-frag of step tl=0.
        bf16x8 axc = *(const bf16x8*)&xbuf[0][tn][q * 8];

        #pragma unroll 2
        for (int tl = 0; tl < T_CHUNK; ++tl) {
            const int t  = tc * T_CHUNK + tl;
            const int rb = t & 1, wb = rb ^ 1;
            // issue ALL step loads together: h frags + next step's x frag.
            // (reads byte-identical to R15; they serve as the B-operand now)
            const bf16x8 a0  = *(const bf16x8*)&hbuf[rb][tn][q * 8];       // h k0..31
            const bf16x8 a1  = *(const bf16x8*)&hbuf[rb][tn][32 + q * 8];  // h k32..63
            const bf16x8 axn = *(const bf16x8*)&xbuf[(tl + 1) & (T_CHUNK - 1)][tn][q * 8];

            __builtin_amdgcn_s_setprio(1);
            // SWAPPED orientation: mfma(W-frag, data-frag, C). x-contribution
            // first from register-carried axc (no lgkm wait).
            f32x4 acc[4];
            #pragma unroll
            for (int g = 0; g < 4; ++g)
                acc[g] = __builtin_amdgcn_mfma_f32_16x16x32_bf16(wf[g][2], axc, biasC[g], 0, 0, 0);
            #pragma unroll
            for (int g = 0; g < 4; ++g)
                acc[g] = __builtin_amdgcn_mfma_f32_16x16x32_bf16(wf[g][0], a0, acc[g], 0, 0, 0);
            #pragma unroll
            for (int g = 0; g < 4; ++g)
                acc[g] = __builtin_amdgcn_mfma_f32_16x16x32_bf16(wf[g][1], a1, acc[g], 0, 0, 0);
            __builtin_amdgcn_s_setprio(0);

            // gate trans phase; acc[g][r] = gate g, batch tn, unit urow+r.
            #pragma unroll
            for (int r = 0; r < 4; ++r) {
                const float gi  = sig_pre(acc[0][r]);
                const float gf  = sig_pre(acc[1][r]);
                const float rg  = __builtin_amdgcn_rcpf(1.0f + __builtin_amdgcn_exp2f(acc[2][r]));
                const float ggS = __builtin_fmaf(rg, -4.0f * LOG2E, 2.0f * LOG2E);  // 2L*tanh
                const float go  = sig_pre(acc[3][r]);
                cstS[r] = gf * cstS[r] + gi * ggS;
                const float th = 1.0f - 2.0f * __builtin_amdgcn_rcpf(1.0f + __builtin_amdgcn_exp2f(cstS[r]));
                hl[r] = go * th;
            }
            // ONE packed ds_write_b64: h[batch tn][units urow..urow+3].
            {
                const unsigned int lo = (unsigned int)f2bf(hl[0]) | ((unsigned int)f2bf(hl[1]) << 16);
                const unsigned int hi = (unsigned int)f2bf(hl[2]) | ((unsigned int)f2bf(hl[3]) << 16);
                uint2 pk; pk.x = lo; pk.y = hi;
                *(uint2*)&hbuf[wb][tn][urow] = pk;
            }

            axc = axn;  // carry next step's x frag (register rename)
            __syncthreads();
        }
    }

    // epilogue: out[b][j] = h_T(fp32) . Wfc[j,:] + bfc[j]
    // lane holds h_T for batch tn, units urow..urow+3 (contiguous row segment)
    #pragma unroll
    for (int r = 0; r < 4; ++r) hfin[tn][urow + r] = hl[r];
    __syncthreads();
    if (tid < B_TILE * 8) {
        const int m = tid >> 3, j = tid & 7;
        float s = ldin<F32>(bfcv, j);
        #pragma unroll
        for (int k = 0; k < HSZ; ++k) s += hfin[m][k] * ldin<F32>(Wfcv, j * HSZ + k);
        const size_t o = (size_t)(b0 + m) * 8 + j;
        if (F32) ((float*)outv)[o] = s;
        else     ((unsigned short*)outv)[o] = f2bf(s);
    }
}

__global__ __launch_bounds__(256, 2) void lstm_fused(
    const void* __restrict__ x, const void* __restrict__ Wih,
    const void* __restrict__ Whh, const void* __restrict__ bih,
    const void* __restrict__ bhh, const void* __restrict__ Wfc,
    const void* __restrict__ bfc, void* __restrict__ out)
{
    __shared__ unsigned short hbuf[2][B_TILE][HPAD];
    __shared__ unsigned short xbuf[T_CHUNK][B_TILE][40];
    __shared__ float hfin[B_TILE][HSZ + 4];

    // dtype sniff (guard): fp32 data read as uint16 halves has mantissa-garbage
    // halves decoding to huge-exponent bf16s; real bf16 data never exceeds 2^17.
    const unsigned short* xu = (const unsigned short*)x;
    const int lane = threadIdx.x & 63;
    const unsigned short s0 = xu[lane * 2];
    const unsigned short s1 = xu[lane * 2 + 1];
    const int big = (((s0 >> 7) & 0xFF) >= 0x90) || (((s1 >> 7) & 0xFF) >= 0x90);
    const bool isf32 = __any(big) != 0;

    if (isf32) run_body<true >(x, Wih, Whh, bih, bhh, Wfc, bfc, out, hbuf, xbuf, hfin);
    else       run_body<false>(x, Wih, Whh, bih, bhh, Wfc, bfc, out, hbuf, xbuf, hfin);
}

extern "C" void kernel_launch(void* const* d_in, const int* in_sizes, int n_in,
                              void* d_out, int out_size, void* d_ws, size_t ws_size,
                              hipStream_t stream) {
    lstm_fused<<<dim3(B_TOT / B_TILE), dim3(256), 0, stream>>>(
        d_in[0], d_in[1], d_in[2], d_in[3], d_in[4], d_in[5], d_in[6], d_out);
}

// Round 10
// 261.008 us; speedup vs baseline: 1.0275x; 1.0275x over previous
//
#include <hip/hip_runtime.h>
#include <stdint.h>

// LSTM fused: B=8192, T=128, I=32, H=64, OUT=8. fp32 internal state, bf16 MFMA.
// R17 (resubmit — previous bench died on infra: "container failed twice").
// R17 = R15 (best, 126.6us) reverted exactly, + two low-risk serial-chain
// trims:
//   (1) s_setprio(1) extended through the gate phase and the per-r h-writes
//       (drop to 0 just before the barrier). Phase-skewed sibling block
//       yields issue slots to the wave on its block's critical path (m191
//       attn-positive mechanism); neutral when in-phase.
//   (2) #pragma unroll 4 on the step loop (rb/wb/nt + addresses become
//       compile-time over 4 steps; longer scheduling window).
// R16 post-mortem (REVERTED): swapped-orientation + packed ds_write_b64
// regressed 126.6->135.8us. The single packed write serialized the step tail
// (all 4 gate chains must finish before any write; R15's per-r scattered
// writes overlap chain r+1). Ledger: per-r incremental h-writes are
// load-bearing; do not pack the write tail.
// Parallelism ledger (closed): 8192 batches x 64 units / (16x16 per-wave
// full-efficiency tile) = 2048 waves = exactly 2/SIMD. Finer slicing makes
// garbage lanes (R12 154us), coarser starves SIMDs (R13 185us), wider
// barriers convoy (R9 184us). Structure frozen at 4-wave/16-batch blocks.
// R15 ledger: {reg-carried x-frag, accx at step top covering a0/a1 lgkm,
// cst in 2log2e domain}; R14: {exp2 scale folded into W/bias, setprio};
// R11: {loads hoisted to step top, dependent MFMAs off the lgkm wait};
// R10: bank conflicts off-path, HPAD=144 known-good (16B-aligned rows).
// NaN ledger: R1/R5/R7 (vector weight loads, plain body) and R6 (K=16 f16)
// all NaN'd; R2/R3/R8/R11/R14/R15 (scalar loads + sniff dispatcher) passed.
// Do not reintroduce those factors without an isolated A/B.

#define T_STEPS 128
#define ISZ 32
#define HSZ 64
#define B_TOT 8192
#define B_TILE 16
#define T_CHUNK 32
#define HPAD 144

typedef short bf16x8 __attribute__((ext_vector_type(8)));
typedef float f32x4 __attribute__((ext_vector_type(4)));

#define LOG2E 1.44269504088896340736f

__device__ __forceinline__ float bf2f(unsigned short s) {
    union { unsigned int u; float f; } v; v.u = ((unsigned int)s) << 16; return v.f;
}
__device__ __forceinline__ unsigned short f2bf(float f) {
    union { float f; unsigned int u; } v; v.f = f;
    unsigned int u = v.u;
    return (unsigned short)((u + 0x7fffu + ((u >> 16) & 1u)) >> 16);  // RNE
}
// prescaled-gate helpers: z already carries the exp2 scale (folded into W).
// sig_pre: z = -LOG2E*x -> sigmoid(x). z->+inf: exp2->inf, rcp->0. Safe.
__device__ __forceinline__ float sig_pre(float z) {
    return __builtin_amdgcn_rcpf(1.0f + __builtin_amdgcn_exp2f(z));
}

template <bool F32>
__device__ __forceinline__ float ldin(const void* p, size_t i) {
    if (F32) return ((const float*)p)[i];
    return bf2f(((const unsigned short*)p)[i]);
}

template <bool F32>
__device__ __forceinline__ void run_body(
    const void* xv, const void* Wihv, const void* Whhv, const void* bihv,
    const void* bhhv, const void* Wfcv, const void* bfcv, void* outv,
    unsigned short (&hbuf)[2][B_TILE][HPAD],
    unsigned short (&xbuf)[T_CHUNK][B_TILE][40],
    float (&hfin)[B_TILE][HSZ + 4])
{
    const int tid  = threadIdx.x;
    const int wid  = tid >> 6;
    const int lane = tid & 63;
    const int q    = lane >> 4;   // A/B frag k-quad; C/D row-quad
    const int tn   = lane & 15;   // A: batch row m; B/C: unit col n
    const int u    = wid * 16 + tn;
    const int b0   = blockIdx.x * B_TILE;

    // B-operand weight frags, loaded once (scalar loads — see NaN ledger).
    // Exp2 scale folded in: i/f/o rows x (-LOG2E), g rows x (+2*LOG2E),
    // applied in fp32 BEFORE the single bf16 rounding (same error profile).
    bf16x8 wf[4][3];
    f32x4 biasC[4];   // bias broadcast into a C-operand vector: no acc-init movs
    #pragma unroll
    for (int g = 0; g < 4; ++g) {
        const float sc = (g == 2) ? (2.0f * LOG2E) : (-LOG2E);
        const int row = g * HSZ + u;
        #pragma unroll
        for (int j = 0; j < 8; ++j) {
            wf[g][0][j] = (short)f2bf(sc * ldin<F32>(Whhv, row * HSZ + q * 8 + j));
            wf[g][1][j] = (short)f2bf(sc * ldin<F32>(Whhv, row * HSZ + 32 + q * 8 + j));
            wf[g][2][j] = (short)f2bf(sc * ldin<F32>(Wihv, row * ISZ + q * 8 + j));
        }
        const float b = sc * (ldin<F32>(bihv, row) + ldin<F32>(bhhv, row));
        #pragma unroll
        for (int e = 0; e < 4; ++e) biasC[g][e] = b;
    }

    // h(0) = 0
    for (int i = tid; i < 2 * B_TILE * HPAD; i += 256) ((unsigned short*)hbuf)[i] = 0;

    // c-state kept in the 2*log2e domain (cstS = 2*LOG2E * c).
    float cstS[4] = {0.f, 0.f, 0.f, 0.f};
    float hl[4]   = {0.f, 0.f, 0.f, 0.f};

    for (int tc = 0; tc < T_STEPS / T_CHUNK; ++tc) {
        // stage x[b0..+16)[tc*32..+32)[0..32) -> xbuf[t][m][k]; prev chunk's
        // reads finished at the last step's barrier, so no barrier needed here.
        if (F32) {
            const float* xf = (const float*)xv;
            for (int idx = tid; idx < B_TILE * T_CHUNK * 4; idx += 256) {
                const int m  = idx >> 7;
                const int rm = idx & 127;
                const int tl = rm >> 2;
                const int ch = rm & 3;
                const size_t base = ((size_t)(b0 + m) * T_STEPS + (tc * T_CHUNK + tl)) * ISZ + ch * 8;
                const f32x4 v0 = *(const f32x4*)(xf + base);
                const f32x4 v1 = *(const f32x4*)(xf + base + 4);
                bf16x8 w;
                #pragma unroll
                for (int j = 0; j < 4; ++j) {
                    w[j]     = (short)f2bf(v0[j]);
                    w[4 + j] = (short)f2bf(v1[j]);
                }
                *(bf16x8*)&xbuf[tl][m][ch * 8] = w;
            }
        } else {
            const unsigned short* xu = (const unsigned short*)xv;
            for (int idx = tid; idx < B_TILE * T_CHUNK * 4; idx += 256) {
                const int m  = idx >> 7;
                const int rm = idx & 127;
                const int tl = rm >> 2;
                const int ch = rm & 3;
                const uint4 v = *(const uint4*)(xu + ((size_t)(b0 + m) * T_STEPS + (tc * T_CHUNK + tl)) * ISZ + ch * 8);
                *(uint4*)&xbuf[tl][m][ch * 8] = v;
            }
        }
        __syncthreads();

        // chunk prologue: register-carry the x-frag of step tl=0.
        bf16x8 axc = *(const bf16x8*)&xbuf[0][tn][q * 8];

        #pragma unroll 4
        for (int tl = 0; tl < T_CHUNK; ++tl) {
            const int t  = tc * T_CHUNK + tl;
            const int rb = t & 1, wb = rb ^ 1;
            // issue ALL step loads together: h A-frags + next step's x frag.
            // ax_next's lgkm wait is deferred to next iteration's accx MFMAs.
            const bf16x8 a0  = *(const bf16x8*)&hbuf[rb][tn][q * 8];       // h k0..31
            const bf16x8 a1  = *(const bf16x8*)&hbuf[rb][tn][32 + q * 8];  // h k32..63
            const bf16x8 axn = *(const bf16x8*)&xbuf[(tl + 1) & (T_CHUNK - 1)][tn][q * 8];

            __builtin_amdgcn_s_setprio(1);
            // x-contribution FIRST, from register-carried axc (no lgkm wait):
            // its issue+pipe latency covers part of a0/a1's ds_read latency.
            f32x4 acc[4];
            #pragma unroll
            for (int g = 0; g < 4; ++g)
                acc[g] = __builtin_amdgcn_mfma_f32_16x16x32_bf16(axc, wf[g][2], biasC[g], 0, 0, 0);
            #pragma unroll
            for (int g = 0; g < 4; ++g)
                acc[g] = __builtin_amdgcn_mfma_f32_16x16x32_bf16(a0, wf[g][0], acc[g], 0, 0, 0);
            #pragma unroll
            for (int g = 0; g < 4; ++g)
                acc[g] = __builtin_amdgcn_mfma_f32_16x16x32_bf16(a1, wf[g][1], acc[g], 0, 0, 0);

            // gate trans phase (still prio 1: finish the block-critical serial
            // chain ASAP; phase-skewed sibling block fills the issue slots).
            // exp2 args come straight from the MFMA output (scale pre-folded
            // into W). cstS in 2*log2e domain: no head mul on output-tanh.
            #pragma unroll
            for (int r = 0; r < 4; ++r) {
                const float gi  = sig_pre(acc[0][r]);
                const float gf  = sig_pre(acc[1][r]);
                const float rg  = __builtin_amdgcn_rcpf(1.0f + __builtin_amdgcn_exp2f(acc[2][r]));
                const float ggS = __builtin_fmaf(rg, -4.0f * LOG2E, 2.0f * LOG2E);  // 2L*tanh
                const float go  = sig_pre(acc[3][r]);
                cstS[r] = gf * cstS[r] + gi * ggS;
                const float th = 1.0f - 2.0f * __builtin_amdgcn_rcpf(1.0f + __builtin_amdgcn_exp2f(cstS[r]));
                const float hv = go * th;
                hl[r] = hv;
                const int m = q * 4 + r;  // C/D row = batch
                hbuf[wb][m][u] = f2bf(hv);  // per-r incremental write (ledger)
            }
            __builtin_amdgcn_s_setprio(0);

            axc = axn;  // carry next step's x frag (register rename)
            __syncthreads();
        }
    }

    // epilogue: out[b][j] = h_T(fp32) . Wfc[j,:] + bfc[j]
    #pragma unroll
    for (int r = 0; r < 4; ++r) hfin[q * 4 + r][u] = hl[r];
    __syncthreads();
    if (tid < B_TILE * 8) {
        const int m = tid >> 3, j = tid & 7;
        float s = ldin<F32>(bfcv, j);
        #pragma unroll
        for (int k = 0; k < HSZ; ++k) s += hfin[m][k] * ldin<F32>(Wfcv, j * HSZ + k);
        const size_t o = (size_t)(b0 + m) * 8 + j;
        if (F32) ((float*)outv)[o] = s;
        else     ((unsigned short*)outv)[o] = f2bf(s);
    }
}

__global__ __launch_bounds__(256, 2) void lstm_fused(
    const void* __restrict__ x, const void* __restrict__ Wih,
    const void* __restrict__ Whh, const void* __restrict__ bih,
    const void* __restrict__ bhh, const void* __restrict__ Wfc,
    const void* __restrict__ bfc, void* __restrict__ out)
{
    __shared__ unsigned short hbuf[2][B_TILE][HPAD];
    __shared__ unsigned short xbuf[T_CHUNK][B_TILE][40];
    __shared__ float hfin[B_TILE][HSZ + 4];

    // dtype sniff (guard): fp32 data read as uint16 halves has mantissa-garbage
    // halves decoding to huge-exponent bf16s; real bf16 data never exceeds 2^17.
    const unsigned short* xu = (const unsigned short*)x;
    const int lane = threadIdx.x & 63;
    const unsigned short s0 = xu[lane * 2];
    const unsigned short s1 = xu[lane * 2 + 1];
    const int big = (((s0 >> 7) & 0xFF) >= 0x90) || (((s1 >> 7) & 0xFF) >= 0x90);
    const bool isf32 = __any(big) != 0;

    if (isf32) run_body<true >(x, Wih, Whh, bih, bhh, Wfc, bfc, out, hbuf, xbuf, hfin);
    else       run_body<false>(x, Wih, Whh, bih, bhh, Wfc, bfc, out, hbuf, xbuf, hfin);
}

extern "C" void kernel_launch(void* const* d_in, const int* in_sizes, int n_in,
                              void* d_out, int out_size, void* d_ws, size_t ws_size,
                              hipStream_t stream) {
    lstm_fused<<<dim3(B_TOT / B_TILE), dim3(256), 0, stream>>>(
        d_in[0], d_in[1], d_in[2], d_in[3], d_in[4], d_in[5], d_in[6], d_out);
}

// Round 12
// 259.916 us; speedup vs baseline: 1.0318x; 1.0042x over previous
//
#include <hip/hip_runtime.h>
#include <stdint.h>

// LSTM fused: B=8192, T=128, I=32, H=64, OUT=8. fp32 internal state, bf16 MFMA.
// R18 (2nd resubmit — rounds 9 & 11 both died on infra: "container failed
// twice"; round 10 proved the R17 base benches cleanly).
// R18 = R17 (best, 123.5us) with ONE structural deletion: the x LDS-staging
// pipeline is removed. x streams straight from global into a 1-step-deep
// register pipeline (per-lane 16B-aligned global_load_dwordx4 of the frag
// for step t+1, issued at step t; the step-end barrier's vmcnt(0) drain
// makes it ready for step t+1 with ZERO added sync). Flat 128-step loop,
// no chunks, xbuf + staging loop deleted (LDS 54.8K -> ~14K). Rationale:
// x is read-once streaming data; the global->reg->ds_write->barrier->ds_read
// round-trip plus 4 chunk-staging phases (~2.5us) bought nothing over L1/L2;
// axn's removal also shortens every barrier's lgkm drain (writes only).
// F32 cold path (FETCH=66MB proves runtime data is bf16) converts the
// pending f32x4 pair at step-top; kept correct, perf irrelevant.
// R17 ledger: setprio(1) through gates+writes, unroll 4. R16 (REVERTED):
// packed ds_write_b64 serialized the step tail — per-r incremental h-writes
// are load-bearing. Parallelism ledger (closed): 2048 waves = exactly
// 2/SIMD; finer = garbage lanes (R12 154us), coarser = starved SIMDs (R13
// 185us), wider barriers = convoy (R9 184us). R15: {reg-carried x-frag,
// accx at step top covering a0/a1 lgkm, cst in 2log2e domain}; R14: {exp2
// scale folded into W/bias}; R11: {loads hoisted to step top, dependent
// MFMAs off the lgkm wait}; R10: bank conflicts off-path, HPAD=144
// known-good (16B-aligned rows).
// NaN ledger: R1/R5/R7 (vector WEIGHT loads, plain body) and R6 (K=16 f16)
// all NaN'd; R2/R3/R8/R11/R14/R15/R17 (scalar weight loads + sniff
// dispatcher) passed. x was always vector-loaded (uint4 staging) — this
// round keeps that factor, just changes the destination (reg vs LDS).

#define T_STEPS 128
#define ISZ 32
#define HSZ 64
#define B_TOT 8192
#define B_TILE 16
#define HPAD 144

typedef short bf16x8 __attribute__((ext_vector_type(8)));
typedef float f32x4 __attribute__((ext_vector_type(4)));

#define LOG2E 1.44269504088896340736f

__device__ __forceinline__ float bf2f(unsigned short s) {
    union { unsigned int u; float f; } v; v.u = ((unsigned int)s) << 16; return v.f;
}
__device__ __forceinline__ unsigned short f2bf(float f) {
    union { float f; unsigned int u; } v; v.f = f;
    unsigned int u = v.u;
    return (unsigned short)((u + 0x7fffu + ((u >> 16) & 1u)) >> 16);  // RNE
}
// prescaled-gate helpers: z already carries the exp2 scale (folded into W).
// sig_pre: z = -LOG2E*x -> sigmoid(x). z->+inf: exp2->inf, rcp->0. Safe.
__device__ __forceinline__ float sig_pre(float z) {
    return __builtin_amdgcn_rcpf(1.0f + __builtin_amdgcn_exp2f(z));
}

template <bool F32>
__device__ __forceinline__ float ldin(const void* p, size_t i) {
    if (F32) return ((const float*)p)[i];
    return bf2f(((const unsigned short*)p)[i]);
}

template <bool F32>
__device__ __forceinline__ void run_body(
    const void* xv, const void* Wihv, const void* Whhv, const void* bihv,
    const void* bhhv, const void* Wfcv, const void* bfcv, void* outv,
    unsigned short (&hbuf)[2][B_TILE][HPAD],
    float (&hfin)[B_TILE][HSZ + 4])
{
    const int tid  = threadIdx.x;
    const int wid  = tid >> 6;
    const int lane = tid & 63;
    const int q    = lane >> 4;   // A/B frag k-quad; C/D row-quad
    const int tn   = lane & 15;   // A: batch row m; B/C: unit col n
    const int u    = wid * 16 + tn;
    const int b0   = blockIdx.x * B_TILE;

    // B-operand weight frags, loaded once (scalar loads — see NaN ledger).
    // Exp2 scale folded in: i/f/o rows x (-LOG2E), g rows x (+2*LOG2E),
    // applied in fp32 BEFORE the single bf16 rounding (same error profile).
    bf16x8 wf[4][3];
    f32x4 biasC[4];   // bias broadcast into a C-operand vector: no acc-init movs
    #pragma unroll
    for (int g = 0; g < 4; ++g) {
        const float sc = (g == 2) ? (2.0f * LOG2E) : (-LOG2E);
        const int row = g * HSZ + u;
        #pragma unroll
        for (int j = 0; j < 8; ++j) {
            wf[g][0][j] = (short)f2bf(sc * ldin<F32>(Whhv, row * HSZ + q * 8 + j));
            wf[g][1][j] = (short)f2bf(sc * ldin<F32>(Whhv, row * HSZ + 32 + q * 8 + j));
            wf[g][2][j] = (short)f2bf(sc * ldin<F32>(Wihv, row * ISZ + q * 8 + j));
        }
        const float b = sc * (ldin<F32>(bihv, row) + ldin<F32>(bhhv, row));
        #pragma unroll
        for (int e = 0; e < 4; ++e) biasC[g][e] = b;
    }

    // per-lane x frag base (element offset): x[b0+tn][t][q*8 .. q*8+7].
    // 16B-aligned for bf16 (base 64B-mult + q*16B), 32B-aligned for f32.
    const size_t xbase = ((size_t)(b0 + tn) * T_STEPS) * ISZ + q * 8;

    // x register pipeline: pend* holds the (issued) frag for the NEXT step.
    // The per-step barrier's vmcnt(0) drain completes it before use.
    bf16x8 pendb;
    f32x4  pend0, pend1;
    if (F32) {
        const float* xf = (const float*)xv + xbase;
        pend0 = *(const f32x4*)(xf);
        pend1 = *(const f32x4*)(xf + 4);
    } else {
        pendb = *(const bf16x8*)((const unsigned short*)xv + xbase);
    }

    // h(0) = 0
    for (int i = tid; i < 2 * B_TILE * HPAD; i += 256) ((unsigned short*)hbuf)[i] = 0;
    __syncthreads();  // h-zero visible to all waves (also covers ld0 latency)

    // c-state kept in the 2*log2e domain (cstS = 2*LOG2E * c).
    float cstS[4] = {0.f, 0.f, 0.f, 0.f};
    float hl[4]   = {0.f, 0.f, 0.f, 0.f};

    #pragma unroll 4
    for (int t = 0; t < T_STEPS; ++t) {
        const int rb = t & 1, wb = rb ^ 1;
        // issue h A-frag ds_reads FIRST (longest pole; latency covered by
        // the accx MFMAs below — R11/R15 ledger).
        const bf16x8 a0 = *(const bf16x8*)&hbuf[rb][tn][q * 8];       // h k0..31
        const bf16x8 a1 = *(const bf16x8*)&hbuf[rb][tn][32 + q * 8];  // h k32..63

        // materialize this step's x frag from the pending regs (ready: the
        // previous barrier drained vmcnt), then issue next step's load.
        bf16x8 axc;
        if (F32) {
            #pragma unroll
            for (int j = 0; j < 4; ++j) {
                axc[j]     = (short)f2bf(pend0[j]);
                axc[4 + j] = (short)f2bf(pend1[j]);
            }
        } else {
            axc = pendb;
        }
        const int t1 = (t < T_STEPS - 1) ? t + 1 : t;  // clamp: last re-load harmless
        if (F32) {
            const float* xf = (const float*)xv + xbase + (size_t)t1 * ISZ;
            pend0 = *(const f32x4*)(xf);
            pend1 = *(const f32x4*)(xf + 4);
        } else {
            pendb = *(const bf16x8*)((const unsigned short*)xv + xbase + (size_t)t1 * ISZ);
        }

        __builtin_amdgcn_s_setprio(1);
        // x-contribution FIRST, from registers (no wait): its issue+pipe
        // latency covers part of a0/a1's ds_read latency.
        f32x4 acc[4];
        #pragma unroll
        for (int g = 0; g < 4; ++g)
            acc[g] = __builtin_amdgcn_mfma_f32_16x16x32_bf16(axc, wf[g][2], biasC[g], 0, 0, 0);
        #pragma unroll
        for (int g = 0; g < 4; ++g)
            acc[g] = __builtin_amdgcn_mfma_f32_16x16x32_bf16(a0, wf[g][0], acc[g], 0, 0, 0);
        #pragma unroll
        for (int g = 0; g < 4; ++g)
            acc[g] = __builtin_amdgcn_mfma_f32_16x16x32_bf16(a1, wf[g][1], acc[g], 0, 0, 0);

        // gate trans phase (still prio 1: finish the block-critical serial
        // chain ASAP). exp2 args come straight from the MFMA output (scale
        // pre-folded into W). cstS in 2*log2e domain: no head mul on the
        // output-tanh chain.
        #pragma unroll
        for (int r = 0; r < 4; ++r) {
            const float gi  = sig_pre(acc[0][r]);
            const float gf  = sig_pre(acc[1][r]);
            const float rg  = __builtin_amdgcn_rcpf(1.0f + __builtin_amdgcn_exp2f(acc[2][r]));
            const float ggS = __builtin_fmaf(rg, -4.0f * LOG2E, 2.0f * LOG2E);  // 2L*tanh
            const float go  = sig_pre(acc[3][r]);
            cstS[r] = gf * cstS[r] + gi * ggS;
            const float th = 1.0f - 2.0f * __builtin_amdgcn_rcpf(1.0f + __builtin_amdgcn_exp2f(cstS[r]));
            const float hv = go * th;
            hl[r] = hv;
            const int m = q * 4 + r;  // C/D row = batch
            hbuf[wb][m][u] = f2bf(hv);  // per-r incremental write (ledger)
        }
        __builtin_amdgcn_s_setprio(0);

        __syncthreads();
    }

    // epilogue: out[b][j] = h_T(fp32) . Wfc[j,:] + bfc[j]
    #pragma unroll
    for (int r = 0; r < 4; ++r) hfin[q * 4 + r][u] = hl[r];
    __syncthreads();
    if (tid < B_TILE * 8) {
        const int m = tid >> 3, j = tid & 7;
        float s = ldin<F32>(bfcv, j);
        #pragma unroll
        for (int k = 0; k < HSZ; ++k) s += hfin[m][k] * ldin<F32>(Wfcv, j * HSZ + k);
        const size_t o = (size_t)(b0 + m) * 8 + j;
        if (F32) ((float*)outv)[o] = s;
        else     ((unsigned short*)outv)[o] = f2bf(s);
    }
}

__global__ __launch_bounds__(256, 2) void lstm_fused(
    const void* __restrict__ x, const void* __restrict__ Wih,
    const void* __restrict__ Whh, const void* __restrict__ bih,
    const void* __restrict__ bhh, const void* __restrict__ Wfc,
    const void* __restrict__ bfc, void* __restrict__ out)
{
    __shared__ unsigned short hbuf[2][B_TILE][HPAD];
    __shared__ float hfin[B_TILE][HSZ + 4];

    // dtype sniff (guard): fp32 data read as uint16 halves has mantissa-garbage
    // halves decoding to huge-exponent bf16s; real bf16 data never exceeds 2^17.
    const unsigned short* xu = (const unsigned short*)x;
    const int lane = threadIdx.x & 63;
    const unsigned short s0 = xu[lane * 2];
    const unsigned short s1 = xu[lane * 2 + 1];
    const int big = (((s0 >> 7) & 0xFF) >= 0x90) || (((s1 >> 7) & 0xFF) >= 0x90);
    const bool isf32 = __any(big) != 0;

    if (isf32) run_body<true >(x, Wih, Whh, bih, bhh, Wfc, bfc, out, hbuf, hfin);
    else       run_body<false>(x, Wih, Whh, bih, bhh, Wfc, bfc, out, hbuf, hfin);
}

extern "C" void kernel_launch(void* const* d_in, const int* in_sizes, int n_in,
                              void* d_out, int out_size, void* d_ws, size_t ws_size,
                              hipStream_t stream) {
    lstm_fused<<<dim3(B_TOT / B_TILE), dim3(256), 0, stream>>>(
        d_in[0], d_in[1], d_in[2], d_in[3], d_in[4], d_in[5], d_in[6], d_out);
}